// Round 1
// baseline (260.830 us; speedup 1.0000x reference)
//
#include <hip/hip_runtime.h>
#include <stdint.h>

#define NB 16
#define NC 512
#define NS 1024
#define NR 32

typedef unsigned short u16;
typedef unsigned int u32;

typedef __attribute__((ext_vector_type(8))) short short8;
typedef __attribute__((ext_vector_type(4))) float f32x4;

__device__ __forceinline__ float bf2f(u16 u) {
    union { u32 i; float f; } c; c.i = ((u32)u) << 16; return c.f;
}
__device__ __forceinline__ u16 f2bf(float f) {
    union { float f; u32 i; } c; c.f = f;
    u32 r = (c.i + 0x7FFFu + ((c.i >> 16) & 1u)) >> 16;
    return (u16)r;
}
__device__ __forceinline__ float sigm(float x) {
    return 1.0f / (1.0f + __expf(-x));
}

// ---------------- spatial mean: s[b,c] = mean_s x[b,c,s] ----------------
__global__ void k_mean(const float* __restrict__ x, float* __restrict__ sm) {
    const int row = blockIdx.x;                 // b*NC + c
    const float4* xr = (const float4*)(x + (long)row * NS);
    const int t = threadIdx.x;                  // 256
    float4 v = xr[t];
    float p = v.x + v.y + v.z + v.w;
    for (int off = 32; off; off >>= 1) p += __shfl_down(p, off);
    __shared__ float red[4];
    if ((t & 63) == 0) red[t >> 6] = p;
    __syncthreads();
    if (t == 0) sm[row] = (red[0] + red[1] + red[2] + red[3]) * (1.0f / 1024.0f);
}

// ---------------- SE MLP: y = sigmoid(relu(s W1^T + b1) W2^T + b2) ------
__global__ void k_se(const float* __restrict__ sm, const float* __restrict__ w1,
                     const float* __restrict__ b1, const float* __restrict__ w2,
                     const float* __restrict__ b2, float* __restrict__ y) {
    const int b = blockIdx.x;
    __shared__ float s_s[NC];
    __shared__ float s_y1[NR];
    const int t = threadIdx.x;                  // 256
    s_s[t] = sm[b * NC + t];
    s_s[t + 256] = sm[b * NC + t + 256];
    __syncthreads();
    if (t < NR) {
        float acc = b1[t];
        for (int c = 0; c < NC; ++c) acc += s_s[c] * w1[t * NC + c];
        s_y1[t] = fmaxf(acc, 0.0f);
    }
    __syncthreads();
    for (int i = 0; i < 2; ++i) {
        int c = t + i * 256;
        float acc = b2[c];
#pragma unroll
        for (int r = 0; r < NR; ++r) acc += s_y1[r] * w2[c * NR + r];
        y[b * NC + c] = 1.0f / (1.0f + expf(-acc));
    }
}

// ------- out32 = x*y  -> bf16 in [c,s] layout AND [s,c] layout ----------
__global__ void k_scale(const float* __restrict__ x, const float* __restrict__ y,
                        u16* __restrict__ o32, u16* __restrict__ o32t) {
    const int b = blockIdx.z;
    const int c0 = blockIdx.y * 32;
    const int s0 = blockIdx.x * 32;
    const int tx = threadIdx.x & 31, ty = threadIdx.x >> 5;  // 32 x 8
    __shared__ float tile[32][33];
    const float* xb = x + (long)b * NC * NS;
#pragma unroll
    for (int it = 0; it < 4; ++it) {
        int c = c0 + ty + it * 8;
        float v = xb[(long)c * NS + s0 + tx] * y[b * NC + c];
        tile[ty + it * 8][tx] = v;
        o32[((long)b * NC + c) * NS + s0 + tx] = f2bf(v);
    }
    __syncthreads();
#pragma unroll
    for (int it = 0; it < 4; ++it) {
        int sr = ty + it * 8;
        o32t[((long)b * NS + (s0 + sr)) * NC + c0 + tx] = f2bf(tile[tx][sr]);
    }
}

// ------------- convert gus (1M) and down_w (0.5M) to bf16 ---------------
__global__ void k_cvt(const float* __restrict__ g, const float* __restrict__ dw,
                      u16* __restrict__ gb, u16* __restrict__ dwb) {
    const int i = blockIdx.x * 256 + threadIdx.x;
    gb[i] = f2bf(g[i]);                          // grid exactly 1048576 threads
    if (i < 524288) dwb[i] = f2bf(dw[i]);
}

// ---------------- bf16 MFMA GEMM: C[m,n] = sum_k A[m,k]*Bt[n,k] ---------
// A: MxK row-major (lda=K), Bt: NxK row-major (ldb=K). M,N mult of 128, K mult of 64.
__device__ __forceinline__ void st_out(float* p, float v) { *p = v; }
__device__ __forceinline__ void st_out(u16* p, float v) { *p = f2bf(v); }

template <typename OT>
__global__ __launch_bounds__(256)
void gemm_bt(const u16* __restrict__ A, const u16* __restrict__ Bt, OT* __restrict__ Co,
             int M, int N, int K, long batA, long batB, long batC) {
    const int b = blockIdx.z;
    const u16* Ab = A + (long)b * batA;
    const u16* Bb = Bt + (long)b * batB;
    OT* Cb = Co + (long)b * batC;
    const int m0 = blockIdx.y * 128, n0 = blockIdx.x * 128;
    __shared__ __align__(16) u16 As[128 * 64];
    __shared__ __align__(16) u16 Bs[128 * 64];
    const int tid = threadIdx.x;
    const int lane = tid & 63, wave = tid >> 6;
    const int wm = (wave >> 1) * 64, wn = (wave & 1) * 64;
    f32x4 acc[4][4];
#pragma unroll
    for (int i = 0; i < 4; ++i)
#pragma unroll
        for (int j = 0; j < 4; ++j) acc[i][j] = (f32x4){0.f, 0.f, 0.f, 0.f};

    int mrow[4], kcol[4];
#pragma unroll
    for (int q = 0; q < 4; ++q) {
        int eoff = wave * 2048 + q * 512 + lane * 8;   // element offset in 128x64 tile
        mrow[q] = eoff >> 6;
        kcol[q] = eoff & 63;
    }

    for (int k0 = 0; k0 < K; k0 += 64) {
#pragma unroll
        for (int q = 0; q < 4; ++q) {
            const u16* ga = Ab + (long)(m0 + mrow[q]) * K + (k0 + kcol[q]);
            __builtin_amdgcn_global_load_lds(
                (const __attribute__((address_space(1))) u32*)ga,
                (__attribute__((address_space(3))) u32*)&As[wave * 2048 + q * 512], 16, 0, 0);
            const u16* gb = Bb + (long)(n0 + mrow[q]) * K + (k0 + kcol[q]);
            __builtin_amdgcn_global_load_lds(
                (const __attribute__((address_space(1))) u32*)gb,
                (__attribute__((address_space(3))) u32*)&Bs[wave * 2048 + q * 512], 16, 0, 0);
        }
        __syncthreads();
#pragma unroll
        for (int kk = 0; kk < 64; kk += 32) {
            const int kidx = kk + ((lane >> 4) << 3);
            short8 af[4], bfr[4];
#pragma unroll
            for (int i = 0; i < 4; ++i)
                af[i] = *(const short8*)&As[(wm + i * 16 + (lane & 15)) * 64 + kidx];
#pragma unroll
            for (int j = 0; j < 4; ++j)
                bfr[j] = *(const short8*)&Bs[(wn + j * 16 + (lane & 15)) * 64 + kidx];
#pragma unroll
            for (int i = 0; i < 4; ++i)
#pragma unroll
                for (int j = 0; j < 4; ++j)
                    acc[i][j] = __builtin_amdgcn_mfma_f32_16x16x32_bf16(af[i], bfr[j], acc[i][j], 0, 0, 0);
        }
        __syncthreads();
    }
    const int col = lane & 15, rq = (lane >> 4) * 4;
#pragma unroll
    for (int i = 0; i < 4; ++i)
#pragma unroll
        for (int j = 0; j < 4; ++j)
#pragma unroll
            for (int r = 0; r < 4; ++r) {
                int row = m0 + wm + i * 16 + rq + r;
                int ncol = n0 + wn + j * 16 + col;
                st_out(&Cb[(long)row * N + ncol], acc[i][j][r]);
            }
}

// ---------------- patch attention, one block per (b, s) ------------------
__global__ void k_attn(const u16* __restrict__ o32t, u16* __restrict__ g2) {
    const int s = blockIdx.x, b = blockIdx.y;
    const int y0 = s >> 5, x0 = s & 31;
    const int t = threadIdx.x;                   // 256, each 2 channels
    const u16* base = o32t + (long)b * NS * NC;
    __shared__ __align__(4) u16 rows[9][NC];
    __shared__ float red[4][9];
    __shared__ float attn_s[9];
    u32 cu = *(const u32*)&base[(long)s * NC + t * 2];
    float c0 = bf2f((u16)(cu & 0xffffu)), c1 = bf2f((u16)(cu >> 16));
    float sc0 = sigm(c0), sc1 = sigm(c1);
    float part[9];
#pragma unroll
    for (int k = 0; k < 9; ++k) {
        int yy = y0 + k / 3 - 1, xx = x0 + k % 3 - 1;
        bool valid = (yy >= 0 && yy < 32 && xx >= 0 && xx < 32);
        u32 u = 0u;
        if (valid) u = *(const u32*)&base[(long)(yy * 32 + xx) * NC + t * 2];
        *(u32*)&rows[k][t * 2] = u;
        if (valid) {
            float v0 = bf2f((u16)(u & 0xffffu)), v1 = bf2f((u16)(u >> 16));
            part[k] = sc0 * sigm(v0) + sc1 * sigm(v1);
        } else {
            part[k] = 0.f;                       // sig-pad is exact 0 outside
        }
    }
#pragma unroll
    for (int k = 0; k < 9; ++k) {
        float p = part[k];
        for (int off = 32; off; off >>= 1) p += __shfl_down(p, off);
        if ((t & 63) == 0) red[t >> 6][k] = p;
    }
    __syncthreads();
    if (t == 0) {
        float lg[9], mx = -1e30f;
#pragma unroll
        for (int k = 0; k < 9; ++k) {
            lg[k] = (red[0][k] + red[1][k] + red[2][k] + red[3][k]) * (1.0f / 512.0f);
            mx = fmaxf(mx, lg[k]);
        }
        float sum = 0.f, e[9];
#pragma unroll
        for (int k = 0; k < 9; ++k) { e[k] = __expf(lg[k] - mx); sum += e[k]; }
        float inv = 1.0f / sum;
#pragma unroll
        for (int k = 0; k < 9; ++k) attn_s[k] = e[k] * inv;
    }
    __syncthreads();
    float g0 = 0.f, g1 = 0.f;
#pragma unroll
    for (int k = 0; k < 9; ++k) {
        u32 u = *(const u32*)&rows[k][t * 2];
        float a = attn_s[k];
        g0 += a * bf2f((u16)(u & 0xffffu));
        g1 += a * bf2f((u16)(u >> 16));
    }
    u32 ou = (u32)f2bf(g0) | ((u32)f2bf(g1) << 16);
    *(u32*)&g2[(long)b * NS * NC + (long)s * NC + t * 2] = ou;
}

// ------- catT[b][s][i] = cat[b][i][s]  (i<512: gbuf flat, else g2 flat) --
__global__ void k_tr(const u16* __restrict__ g, const u16* __restrict__ g2,
                     u16* __restrict__ ct) {
    const int b = blockIdx.z;
    const int i0 = blockIdx.y * 32, s0 = blockIdx.x * 32;
    const int tx = threadIdx.x & 31, ty = threadIdx.x >> 5;
    __shared__ u16 tile[32][33];
    const u16* src = (i0 < 512) ? (g + (long)b * 524288 + (long)i0 * 1024)
                                : (g2 + (long)b * 524288 + (long)(i0 - 512) * 1024);
#pragma unroll
    for (int it = 0; it < 4; ++it) {
        int il = ty + it * 8;
        tile[il][tx] = src[(long)il * 1024 + s0 + tx];
    }
    __syncthreads();
#pragma unroll
    for (int it = 0; it < 4; ++it) {
        int sl = ty + it * 8;
        ct[(long)b * 1048576 + (long)(s0 + sl) * 1024 + i0 + tx] = tile[tx][sl];
    }
}

// -------- InstanceNorm over s (1024) + LeakyReLU(0.2), per (b,o) row -----
__global__ void k_norm(const float* __restrict__ z, float* __restrict__ out) {
    const int row = blockIdx.x;                 // b*NC + o
    const float4* zr = (const float4*)(z + (long)row * NS);
    const int t = threadIdx.x;
    float4 v = zr[t];
    float sm = v.x + v.y + v.z + v.w;
    float sq = v.x * v.x + v.y * v.y + v.z * v.z + v.w * v.w;
    for (int off = 32; off; off >>= 1) { sm += __shfl_down(sm, off); sq += __shfl_down(sq, off); }
    __shared__ float rs[4], rq2[4];
    if ((t & 63) == 0) { rs[t >> 6] = sm; rq2[t >> 6] = sq; }
    __syncthreads();
    float tot = rs[0] + rs[1] + rs[2] + rs[3];
    float totq = rq2[0] + rq2[1] + rq2[2] + rq2[3];
    float mu = tot * (1.0f / 1024.0f);
    float var = totq * (1.0f / 1024.0f) - mu * mu;
    float sc = rsqrtf(var + 1e-5f);
    float4 o;
    float a;
    a = (v.x - mu) * sc; o.x = (a >= 0.f) ? a : 0.2f * a;
    a = (v.y - mu) * sc; o.y = (a >= 0.f) ? a : 0.2f * a;
    a = (v.z - mu) * sc; o.z = (a >= 0.f) ? a : 0.2f * a;
    a = (v.w - mu) * sc; o.w = (a >= 0.f) ? a : 0.2f * a;
    ((float4*)(out + (long)row * NS))[t] = o;
}

extern "C" void kernel_launch(void* const* d_in, const int* in_sizes, int n_in,
                              void* d_out, int out_size, void* d_ws, size_t ws_size,
                              hipStream_t stream) {
    const float* x   = (const float*)d_in[0];
    const float* w1  = (const float*)d_in[1];
    const float* b1  = (const float*)d_in[2];
    const float* w2  = (const float*)d_in[3];
    const float* b2  = (const float*)d_in[4];
    const float* dw  = (const float*)d_in[5];
    const float* gus = (const float*)d_in[6];
    float* out = (float*)d_out;
    char* ws = (char*)d_ws;

    // workspace layout (67.1 MB, region A/B overlays)
    float* sm_buf = (float*)(ws + 0);                    // 32 KB
    float* y_buf  = (float*)(ws + 32768);                // 32 KB
    u16* gusbf    = (u16*)(ws + 65536);                  // 2 MB
    u16* dwbf     = (u16*)(ws + 2162688);                // 1 MB
    char* regA    = ws + 3211264;                        // 32 MB region A
    u16* o32      = (u16*)regA;                          //   out32 bf16 [b][c][s]
    u16* o32t     = (u16*)(regA + 16777216);             //   out32 bf16 [b][s][c]
    u16* catT     = (u16*)regA;                          //   reuse A: catT [b][s][i]
    char* regB    = ws + 36765696;                       // 32 MB region B
    u16* gbuf     = (u16*)regB;                          //   gus_out flat bf16
    u16* g2b      = (u16*)(regB + 16777216);             //   out_csa flat bf16
    float* Z      = (float*)regB;                        //   reuse B: z fp32

    k_mean<<<dim3(NB * NC), dim3(256), 0, stream>>>(x, sm_buf);
    k_se<<<dim3(NB), dim3(256), 0, stream>>>(sm_buf, w1, b1, w2, b2, y_buf);
    k_scale<<<dim3(32, 16, NB), dim3(256), 0, stream>>>(x, y_buf, o32, o32t);
    k_cvt<<<dim3(4096), dim3(256), 0, stream>>>(gus, dw, gusbf, dwbf);
    // G[p,ch] = sum_s gus[p,s] * out32[ch,s] : M=1024, N=512, K=1024
    gemm_bt<u16><<<dim3(4, 8, NB), dim3(256), 0, stream>>>(
        gusbf, o32, gbuf, 1024, 512, 1024, 0L, (long)NC * NS, (long)NC * NS);
    k_attn<<<dim3(NS, NB), dim3(256), 0, stream>>>(o32t, g2b);
    k_tr<<<dim3(32, 32, NB), dim3(256), 0, stream>>>(gbuf, g2b, catT);
    // Z[o,s] = sum_i dw[o,i] * catT[s,i] : M=512, N=1024, K=1024
    gemm_bt<float><<<dim3(8, 4, NB), dim3(256), 0, stream>>>(
        dwbf, catT, Z, 512, 1024, 1024, 0L, (long)NS * 1024, (long)NC * NS);
    k_norm<<<dim3(NB * NC), dim3(256), 0, stream>>>(Z, out);
}

// Round 2
// 224.868 us; speedup vs baseline: 1.1599x; 1.1599x over previous
//
#include <hip/hip_runtime.h>
#include <stdint.h>

#define NB 16
#define NC 512
#define NS 1024
#define NR 32

typedef unsigned short u16;
typedef unsigned int u32;

typedef __attribute__((ext_vector_type(8))) short short8;
typedef __attribute__((ext_vector_type(4))) float f32x4;

__device__ __forceinline__ float bf2f(u16 u) {
    union { u32 i; float f; } c; c.i = ((u32)u) << 16; return c.f;
}
__device__ __forceinline__ u16 f2bf(float f) {
    union { float f; u32 i; } c; c.f = f;
    u32 r = (c.i + 0x7FFFu + ((c.i >> 16) & 1u)) >> 16;
    return (u16)r;
}
__device__ __forceinline__ float sigm(float x) {
    return 1.0f / (1.0f + __expf(-x));
}

// ---------------- spatial mean: s[b,c] = mean_s x[b,c,s] ----------------
__global__ void k_mean(const float* __restrict__ x, float* __restrict__ sm) {
    const int row = blockIdx.x;                 // b*NC + c
    const float4* xr = (const float4*)(x + (long)row * NS);
    const int t = threadIdx.x;                  // 256
    float4 v = xr[t];
    float p = v.x + v.y + v.z + v.w;
    for (int off = 32; off; off >>= 1) p += __shfl_down(p, off);
    __shared__ float red[4];
    if ((t & 63) == 0) red[t >> 6] = p;
    __syncthreads();
    if (t == 0) sm[row] = (red[0] + red[1] + red[2] + red[3]) * (1.0f / 1024.0f);
}

// ---------------- SE MLP: y = sigmoid(relu(s W1^T + b1) W2^T + b2) ------
__global__ void k_se(const float* __restrict__ sm, const float* __restrict__ w1,
                     const float* __restrict__ b1, const float* __restrict__ w2,
                     const float* __restrict__ b2, float* __restrict__ y) {
    const int b = blockIdx.x;
    __shared__ float s_s[NC];
    __shared__ float s_y1[NR];
    const int t = threadIdx.x;                  // 256
    s_s[t] = sm[b * NC + t];
    s_s[t + 256] = sm[b * NC + t + 256];
    __syncthreads();
    if (t < NR) {
        float acc = b1[t];
        for (int c = 0; c < NC; ++c) acc += s_s[c] * w1[t * NC + c];
        s_y1[t] = fmaxf(acc, 0.0f);
    }
    __syncthreads();
    for (int i = 0; i < 2; ++i) {
        int c = t + i * 256;
        float acc = b2[c];
#pragma unroll
        for (int r = 0; r < NR; ++r) acc += s_y1[r] * w2[c * NR + r];
        y[b * NC + c] = 1.0f / (1.0f + expf(-acc));
    }
}

// out32 = x*y -> bf16 [c,s] (o32), [s,c] (o32t), and sigmoid in [s,c] (sig_t)
__global__ void k_scale(const float* __restrict__ x, const float* __restrict__ y,
                        u16* __restrict__ o32, u16* __restrict__ o32t,
                        u16* __restrict__ sig_t) {
    const int b = blockIdx.z;
    const int c0 = blockIdx.y * 32;
    const int s0 = blockIdx.x * 32;
    const int tx = threadIdx.x & 31, ty = threadIdx.x >> 5;  // 32 x 8
    __shared__ float tile[32][33];
    const float* xb = x + (long)b * NC * NS;
#pragma unroll
    for (int it = 0; it < 4; ++it) {
        int c = c0 + ty + it * 8;
        float v = xb[(long)c * NS + s0 + tx] * y[b * NC + c];
        tile[ty + it * 8][tx] = v;
        o32[((long)b * NC + c) * NS + s0 + tx] = f2bf(v);
    }
    __syncthreads();
#pragma unroll
    for (int it = 0; it < 4; ++it) {
        int sr = ty + it * 8;
        float tv = tile[tx][sr];
        long idx = ((long)b * NS + (s0 + sr)) * NC + c0 + tx;
        o32t[idx] = f2bf(tv);
        sig_t[idx] = f2bf(sigm(tv));
    }
}

// ------------- convert gus (1M) and down_w (0.5M) to bf16 ---------------
__global__ void k_cvt(const float* __restrict__ g, const float* __restrict__ dw,
                      u16* __restrict__ gb, u16* __restrict__ dwb) {
    const int i = blockIdx.x * 256 + threadIdx.x;
    gb[i] = f2bf(g[i]);                          // grid exactly 1048576 threads
    if (i < 524288) dwb[i] = f2bf(dw[i]);
}

// ---------------- bf16 MFMA GEMM: C[m,n] = sum_k A[m,k]*Bt[n,k] ---------
__device__ __forceinline__ void st_out(float* p, float v) { *p = v; }
__device__ __forceinline__ void st_out(u16* p, float v) { *p = f2bf(v); }

template <typename OT>
__global__ __launch_bounds__(256)
void gemm_bt(const u16* __restrict__ A, const u16* __restrict__ Bt, OT* __restrict__ Co,
             int M, int N, int K, long batA, long batB, long batC) {
    const int b = blockIdx.z;
    const u16* Ab = A + (long)b * batA;
    const u16* Bb = Bt + (long)b * batB;
    OT* Cb = Co + (long)b * batC;
    const int m0 = blockIdx.y * 128, n0 = blockIdx.x * 128;
    __shared__ __align__(16) u16 As[128 * 64];
    __shared__ __align__(16) u16 Bs[128 * 64];
    const int tid = threadIdx.x;
    const int lane = tid & 63, wave = tid >> 6;
    const int wm = (wave >> 1) * 64, wn = (wave & 1) * 64;
    f32x4 acc[4][4];
#pragma unroll
    for (int i = 0; i < 4; ++i)
#pragma unroll
        for (int j = 0; j < 4; ++j) acc[i][j] = (f32x4){0.f, 0.f, 0.f, 0.f};

    int mrow[4], kcol[4];
#pragma unroll
    for (int q = 0; q < 4; ++q) {
        int eoff = wave * 2048 + q * 512 + lane * 8;   // element offset in 128x64 tile
        mrow[q] = eoff >> 6;
        kcol[q] = eoff & 63;
    }

    for (int k0 = 0; k0 < K; k0 += 64) {
#pragma unroll
        for (int q = 0; q < 4; ++q) {
            const u16* ga = Ab + (long)(m0 + mrow[q]) * K + (k0 + kcol[q]);
            __builtin_amdgcn_global_load_lds(
                (const __attribute__((address_space(1))) u32*)ga,
                (__attribute__((address_space(3))) u32*)&As[wave * 2048 + q * 512], 16, 0, 0);
            const u16* gb = Bb + (long)(n0 + mrow[q]) * K + (k0 + kcol[q]);
            __builtin_amdgcn_global_load_lds(
                (const __attribute__((address_space(1))) u32*)gb,
                (__attribute__((address_space(3))) u32*)&Bs[wave * 2048 + q * 512], 16, 0, 0);
        }
        __syncthreads();
#pragma unroll
        for (int kk = 0; kk < 64; kk += 32) {
            const int kidx = kk + ((lane >> 4) << 3);
            short8 af[4], bfr[4];
#pragma unroll
            for (int i = 0; i < 4; ++i)
                af[i] = *(const short8*)&As[(wm + i * 16 + (lane & 15)) * 64 + kidx];
#pragma unroll
            for (int j = 0; j < 4; ++j)
                bfr[j] = *(const short8*)&Bs[(wn + j * 16 + (lane & 15)) * 64 + kidx];
#pragma unroll
            for (int i = 0; i < 4; ++i)
#pragma unroll
                for (int j = 0; j < 4; ++j)
                    acc[i][j] = __builtin_amdgcn_mfma_f32_16x16x32_bf16(af[i], bfr[j], acc[i][j], 0, 0, 0);
        }
        __syncthreads();
    }
    const int col = lane & 15, rq = (lane >> 4) * 4;
#pragma unroll
    for (int i = 0; i < 4; ++i)
#pragma unroll
        for (int j = 0; j < 4; ++j)
#pragma unroll
            for (int r = 0; r < 4; ++r) {
                int row = m0 + wm + i * 16 + rq + r;
                int ncol = n0 + wn + j * 16 + col;
                st_out(&Cb[(long)row * N + ncol], acc[i][j][r]);
            }
}

// ------- patch attention: one wave per (b, s); lane covers 8 channels ----
__global__ __launch_bounds__(256)
void k_attn(const u16* __restrict__ sig_t, const u16* __restrict__ o32t,
            u16* __restrict__ g2) {
    const int wave = threadIdx.x >> 6, lane = threadIdx.x & 63;
    const int s = blockIdx.x * 4 + wave;
    const int b = blockIdx.y;
    const int y0 = s >> 5, x0 = s & 31;
    const long base = (long)b * NS * NC;
    const int coff = lane * 8;

    // center sigmoid values (8 channels)
    short8 csv = *(const short8*)&sig_t[base + (long)s * NC + coff];
    float sc[8];
#pragma unroll
    for (int j = 0; j < 8; ++j) sc[j] = bf2f((u16)csv[j]);

    float part[9];
    short8 raw[9];
#pragma unroll
    for (int k = 0; k < 9; ++k) {
        int yy = y0 + k / 3 - 1, xx = x0 + k % 3 - 1;
        bool valid = (yy >= 0 && yy < 32 && xx >= 0 && xx < 32);
        if (valid) {
            long roff = base + (long)(yy * 32 + xx) * NC + coff;
            short8 sv = *(const short8*)&sig_t[roff];
            raw[k] = *(const short8*)&o32t[roff];
            float p = 0.f;
#pragma unroll
            for (int j = 0; j < 8; ++j) p += sc[j] * bf2f((u16)sv[j]);
            part[k] = p;
        } else {
            raw[k] = (short8){0, 0, 0, 0, 0, 0, 0, 0};
            part[k] = 0.f;
        }
    }
    // reduce 9 partials across the wave (lane 0 gets totals)
#pragma unroll
    for (int k = 0; k < 9; ++k)
        for (int off = 32; off; off >>= 1) part[k] += __shfl_down(part[k], off);

    if (lane == 0) {
        float mx = -1e30f;
#pragma unroll
        for (int k = 0; k < 9; ++k) { part[k] *= (1.0f / 512.0f); mx = fmaxf(mx, part[k]); }
        float sum = 0.f;
#pragma unroll
        for (int k = 0; k < 9; ++k) { part[k] = __expf(part[k] - mx); sum += part[k]; }
        float inv = 1.0f / sum;
#pragma unroll
        for (int k = 0; k < 9; ++k) part[k] *= inv;
    }
    float g[8] = {0.f, 0.f, 0.f, 0.f, 0.f, 0.f, 0.f, 0.f};
#pragma unroll
    for (int k = 0; k < 9; ++k) {
        float a = __shfl(part[k], 0);
#pragma unroll
        for (int j = 0; j < 8; ++j) g[j] += a * bf2f((u16)raw[k][j]);
    }
    short8 ov;
#pragma unroll
    for (int j = 0; j < 8; ++j) ov[j] = (short)f2bf(g[j]);
    *(short8*)&g2[base + (long)s * NC + coff] = ov;
}

// ------- catT[b][s][i] = cat[b][i][s]  (i<512: gbuf flat, else g2 flat) --
__global__ void k_tr(const u16* __restrict__ g, const u16* __restrict__ g2,
                     u16* __restrict__ ct) {
    const int b = blockIdx.z;
    const int i0 = blockIdx.y * 32, s0 = blockIdx.x * 32;
    const int tx = threadIdx.x & 31, ty = threadIdx.x >> 5;
    __shared__ u16 tile[32][33];
    const u16* src = (i0 < 512) ? (g + (long)b * 524288 + (long)i0 * 1024)
                                : (g2 + (long)b * 524288 + (long)(i0 - 512) * 1024);
#pragma unroll
    for (int it = 0; it < 4; ++it) {
        int il = ty + it * 8;
        tile[il][tx] = src[(long)il * 1024 + s0 + tx];
    }
    __syncthreads();
#pragma unroll
    for (int it = 0; it < 4; ++it) {
        int sl = ty + it * 8;
        ct[(long)b * 1048576 + (long)(s0 + sl) * 1024 + i0 + tx] = tile[tx][sl];
    }
}

// -------- InstanceNorm over s (1024) + LeakyReLU(0.2), per (b,o) row -----
__global__ void k_norm(const float* __restrict__ z, float* __restrict__ out) {
    const int row = blockIdx.x;                 // b*NC + o
    const float4* zr = (const float4*)(z + (long)row * NS);
    const int t = threadIdx.x;
    float4 v = zr[t];
    float sm = v.x + v.y + v.z + v.w;
    float sq = v.x * v.x + v.y * v.y + v.z * v.z + v.w * v.w;
    for (int off = 32; off; off >>= 1) { sm += __shfl_down(sm, off); sq += __shfl_down(sq, off); }
    __shared__ float rs[4], rq2[4];
    if ((t & 63) == 0) { rs[t >> 6] = sm; rq2[t >> 6] = sq; }
    __syncthreads();
    float tot = rs[0] + rs[1] + rs[2] + rs[3];
    float totq = rq2[0] + rq2[1] + rq2[2] + rq2[3];
    float mu = tot * (1.0f / 1024.0f);
    float var = totq * (1.0f / 1024.0f) - mu * mu;
    float sc = rsqrtf(var + 1e-5f);
    float4 o;
    float a;
    a = (v.x - mu) * sc; o.x = (a >= 0.f) ? a : 0.2f * a;
    a = (v.y - mu) * sc; o.y = (a >= 0.f) ? a : 0.2f * a;
    a = (v.z - mu) * sc; o.z = (a >= 0.f) ? a : 0.2f * a;
    a = (v.w - mu) * sc; o.w = (a >= 0.f) ? a : 0.2f * a;
    ((float4*)(out + (long)row * NS))[t] = o;
}

extern "C" void kernel_launch(void* const* d_in, const int* in_sizes, int n_in,
                              void* d_out, int out_size, void* d_ws, size_t ws_size,
                              hipStream_t stream) {
    const float* x   = (const float*)d_in[0];
    const float* w1  = (const float*)d_in[1];
    const float* b1  = (const float*)d_in[2];
    const float* w2  = (const float*)d_in[3];
    const float* b2  = (const float*)d_in[4];
    const float* dw  = (const float*)d_in[5];
    const float* gus = (const float*)d_in[6];
    float* out = (float*)d_out;
    char* ws = (char*)d_ws;

    // workspace layout (67.1 MB, region A/B overlays)
    float* sm_buf = (float*)(ws + 0);                    // 32 KB
    float* y_buf  = (float*)(ws + 32768);                // 32 KB
    u16* gusbf    = (u16*)(ws + 65536);                  // 2 MB
    u16* dwbf     = (u16*)(ws + 2162688);                // 1 MB
    char* regA    = ws + 3211264;                        // 32 MB region A
    u16* o32      = (u16*)regA;                          //   out32 bf16 [b][c][s]
    u16* o32t     = (u16*)(regA + 16777216);             //   out32 bf16 [b][s][c]
    u16* catT     = (u16*)regA;                          //   reuse A: catT [b][s][i]
    char* regB    = ws + 36765696;                       // 32 MB region B
    u16* sig_t    = (u16*)regB;                          //   sigmoid(out32) [b][s][c] (dies before gemm1)
    u16* gbuf     = (u16*)regB;                          //   gus_out flat bf16 (after attn)
    u16* g2b      = (u16*)(regB + 16777216);             //   out_csa flat bf16
    float* Z      = (float*)regB;                        //   reuse B: z fp32

    k_mean<<<dim3(NB * NC), dim3(256), 0, stream>>>(x, sm_buf);
    k_se<<<dim3(NB), dim3(256), 0, stream>>>(sm_buf, w1, b1, w2, b2, y_buf);
    k_scale<<<dim3(32, 16, NB), dim3(256), 0, stream>>>(x, y_buf, o32, o32t, sig_t);
    k_cvt<<<dim3(4096), dim3(256), 0, stream>>>(gus, dw, gusbf, dwbf);
    // attention first: sig_t (regB slot 0) dies here, then gemm1 writes gbuf there
    k_attn<<<dim3(256, NB), dim3(256), 0, stream>>>(sig_t, o32t, g2b);
    // G[p,ch] = sum_s gus[p,s] * out32[ch,s] : M=1024, N=512, K=1024
    gemm_bt<u16><<<dim3(4, 8, NB), dim3(256), 0, stream>>>(
        gusbf, o32, gbuf, 1024, 512, 1024, 0L, (long)NC * NS, (long)NC * NS);
    k_tr<<<dim3(32, 32, NB), dim3(256), 0, stream>>>(gbuf, g2b, catT);
    // Z[o,s] = sum_i dw[o,i] * catT[s,i] : M=512, N=1024, K=1024
    gemm_bt<float><<<dim3(8, 4, NB), dim3(256), 0, stream>>>(
        dwbf, catT, Z, 512, 1024, 1024, 0L, (long)NS * 1024, (long)NC * NS);
    k_norm<<<dim3(NB * NC), dim3(256), 0, stream>>>(Z, out);
}